// Round 1
// baseline (2346.045 us; speedup 1.0000x reference)
//
#include <hip/hip_runtime.h>
#include <math.h>

#define BB 4096
#define LL 200
#define EE 128
#define FF 64
#define TM 40          // items per tile
#define NTILES 5       // 5 * 40 = 200
#define HALF_TM 20     // l's owned per thread

// fused: 20 FMAs of acc[j] += w * src[j], src 16B-aligned LDS row slice
__device__ __forceinline__ void fma20(float w, const float* src, float* acc) {
    const float4* s4 = (const float4*)src;
    #pragma unroll
    for (int j = 0; j < 5; ++j) {
        float4 v = s4[j];
        acc[4*j+0] += w * v.x;
        acc[4*j+1] += w * v.y;
        acc[4*j+2] += w * v.z;
        acc[4*j+3] += w * v.w;
    }
}

__device__ __forceinline__ float waveMax(float v) {
    #pragma unroll
    for (int off = 32; off > 0; off >>= 1)
        v = fmaxf(v, __shfl_xor(v, off, 64));
    return v;
}
__device__ __forceinline__ float waveSum(float v) {
    #pragma unroll
    for (int off = 32; off > 0; off >>= 1)
        v += __shfl_xor(v, off, 64);
    return v;
}

__global__ __launch_bounds__(256, 2)
void usernet_fused(const int* __restrict__ user_ids,
                   const int* __restrict__ item_ids,
                   const float* __restrict__ features,
                   const float* __restrict__ user_emb,
                   const float* __restrict__ item_emb,
                   const float* __restrict__ feat_w1,
                   const float* __restrict__ feat_b1,
                   const float* __restrict__ feat_w2,
                   const float* __restrict__ feat_b2,
                   const float* __restrict__ w1,
                   const float* __restrict__ b1,
                   const float* __restrict__ w2,
                   const float* __restrict__ b2,
                   float* __restrict__ out)
{
    __shared__ float s_user[EE];
    __shared__ float s_u1[EE];            // W1a @ user (user part of feat layer1)
    __shared__ float s_u3[EE];            // w1[:, :E] @ user (user part of attn layer1)
    __shared__ float s_feat[FF][TM];      // features tile, transposed [f][l]
    __shared__ float s_item[EE][TM];      // gathered item rows, transposed [k][l]
    __shared__ float s_fx[EE][TM];        // layer1 out [e][l]; reused as p[e][l] for logit
    __shared__ float s_comp[EE][TM];      // layer2 out [e][l]
    __shared__ float s_logits[LL];
    __shared__ float s_red[8];
    __shared__ float s_part[EE];

    const int b    = blockIdx.x;
    const int tid  = threadIdx.x;
    const int e    = tid & (EE - 1);
    const int half = tid >> 7;            // 0 or 1
    const int lbase = half * HALF_TM;

    // ---- phase 0: load user row (512 B) ----
    if (tid < 32) {
        const int uid = user_ids[b];
        ((float4*)s_user)[tid] = ((const float4*)(user_emb + (size_t)uid * EE))[tid];
    }
    __syncthreads();

    // ---- per-row user folds: u1[e] = sum_k feat_w1[e,k]*user[k], u3[e] = sum_k w1[e,k]*user[k]
    {
        const float* wrow = (half == 0) ? (feat_w1 + (size_t)e * (EE + FF))
                                        : (w1      + (size_t)e * (3 * EE));
        float acc = 0.f;
        #pragma unroll 8
        for (int k = 0; k < EE; ++k) acc += wrow[k] * s_user[k];
        if (half == 0) s_u1[e] = acc; else s_u3[e] = acc;
    }
    __syncthreads();

    // ---- item tiles ----
    for (int it = 0; it < NTILES; ++it) {
        const int l0 = it * TM;

        // stage features transposed: [f][l]
        #pragma unroll
        for (int j = 0; j < (TM * FF) / 256; ++j) {      // 10
            int idx = j * 256 + tid;
            int l = idx >> 6;            // / FF
            int f = idx & (FF - 1);
            s_feat[f][l] = features[((size_t)b * LL + l0 + l) * FF + f];
        }
        // gather item rows transposed: [k][l]
        #pragma unroll
        for (int j = 0; j < (TM * EE) / 256; ++j) {      // 20
            int idx = j * 256 + tid;
            int l = idx >> 7;            // / EE
            int k = idx & (EE - 1);
            int id = item_ids[(size_t)b * LL + l0 + l];
            s_item[k][l] = item_emb[(size_t)id * EE + k];
        }
        __syncthreads();

        // ---- layer 1 (features part only; user part pre-folded in u1) ----
        {
            float acc[HALF_TM];
            #pragma unroll
            for (int j = 0; j < HALF_TM; ++j) acc[j] = 0.f;
            const float4* w4 = (const float4*)(feat_w1 + (size_t)e * (EE + FF) + EE);
            #pragma unroll 2
            for (int k4 = 0; k4 < FF / 4; ++k4) {
                float4 wv = w4[k4];
                fma20(wv.x, &s_feat[4*k4+0][lbase], acc);
                fma20(wv.y, &s_feat[4*k4+1][lbase], acc);
                fma20(wv.z, &s_feat[4*k4+2][lbase], acc);
                fma20(wv.w, &s_feat[4*k4+3][lbase], acc);
            }
            const float base = s_u1[e] + feat_b1[e];
            #pragma unroll
            for (int j = 0; j < HALF_TM; ++j) {
                float v = base + acc[j];
                s_fx[e][lbase + j] = v > 0.f ? v : 0.f;
            }
        }
        __syncthreads();

        // ---- layer 2: comp = relu(feat_w2 @ fx + feat_b2) ----
        {
            float acc[HALF_TM];
            #pragma unroll
            for (int j = 0; j < HALF_TM; ++j) acc[j] = 0.f;
            const float4* w4 = (const float4*)(feat_w2 + (size_t)e * EE);
            #pragma unroll 2
            for (int k4 = 0; k4 < EE / 4; ++k4) {
                float4 wv = w4[k4];
                fma20(wv.x, &s_fx[4*k4+0][lbase], acc);
                fma20(wv.y, &s_fx[4*k4+1][lbase], acc);
                fma20(wv.z, &s_fx[4*k4+2][lbase], acc);
                fma20(wv.w, &s_fx[4*k4+3][lbase], acc);
            }
            const float base = feat_b2[e];
            #pragma unroll
            for (int j = 0; j < HALF_TM; ++j) {
                float v = base + acc[j];
                s_comp[e][lbase + j] = v > 0.f ? v : 0.f;
            }
        }
        __syncthreads();

        // ---- layer 3 (item + comp parts; user part pre-folded in u3) + logit fold ----
        {
            float acc[HALF_TM];
            #pragma unroll
            for (int j = 0; j < HALF_TM; ++j) acc[j] = 0.f;
            const float4* wI = (const float4*)(w1 + (size_t)e * (3 * EE) + EE);
            const float4* wC = (const float4*)(w1 + (size_t)e * (3 * EE) + 2 * EE);
            #pragma unroll 2
            for (int k4 = 0; k4 < EE / 4; ++k4) {
                float4 wv = wI[k4];
                fma20(wv.x, &s_item[4*k4+0][lbase], acc);
                fma20(wv.y, &s_item[4*k4+1][lbase], acc);
                fma20(wv.z, &s_item[4*k4+2][lbase], acc);
                fma20(wv.w, &s_item[4*k4+3][lbase], acc);
            }
            #pragma unroll 2
            for (int k4 = 0; k4 < EE / 4; ++k4) {
                float4 wv = wC[k4];
                fma20(wv.x, &s_comp[4*k4+0][lbase], acc);
                fma20(wv.y, &s_comp[4*k4+1][lbase], acc);
                fma20(wv.z, &s_comp[4*k4+2][lbase], acc);
                fma20(wv.w, &s_comp[4*k4+3][lbase], acc);
            }
            const float base = s_u3[e] + b1[e];
            const float w2e  = w2[e];
            #pragma unroll
            for (int j = 0; j < HALF_TM; ++j) {
                float v = base + acc[j];
                v = v > 0.f ? v : 0.f;
                s_fx[e][lbase + j] = w2e * v;   // s_fx reused as p[e][l]
            }
        }
        __syncthreads();

        // logit[l] = b2 + sum_e p[e][l]   (40 lanes, trivial)
        if (tid < TM) {
            float acc = b2[0];
            #pragma unroll 8
            for (int k = 0; k < EE; ++k) acc += s_fx[k][tid];
            s_logits[l0 + tid] = acc;
        }
        __syncthreads();
    }

    // ---- softmax over L=200 ----
    const int wid = tid >> 6;
    float lv = (tid < LL) ? s_logits[tid] : -INFINITY;
    {
        float m = waveMax(lv);
        if ((tid & 63) == 0) s_red[wid] = m;
        __syncthreads();
        if (tid == 0)
            s_red[4] = fmaxf(fmaxf(s_red[0], s_red[1]), fmaxf(s_red[2], s_red[3]));
        __syncthreads();
    }
    const float gmax = s_red[4];
    __syncthreads();
    float ex = (tid < LL) ? __expf(lv - gmax) : 0.f;
    {
        float s = waveSum(ex);
        if ((tid & 63) == 0) s_red[wid] = s;
        __syncthreads();
        if (tid == 0) s_red[4] = s_red[0] + s_red[1] + s_red[2] + s_red[3];
        __syncthreads();
    }
    const float inv = 1.f / s_red[4];
    if (tid < LL) s_logits[tid] = ex * inv;
    __syncthreads();

    // ---- out[b] = user + sum_l attn[l] * item_emb[item_ids[b,l]] ----
    {
        float acc = 0.f;
        const int lstart = half * (LL / 2);
        for (int l = lstart; l < lstart + LL / 2; ++l) {
            const float a = s_logits[l];                       // wave-uniform
            const int  id = item_ids[(size_t)b * LL + l];      // wave-uniform
            acc += a * item_emb[(size_t)id * EE + e];          // coalesced
        }
        if (half == 0) s_part[e] = acc;
        __syncthreads();
        if (half == 1)
            out[(size_t)b * EE + e] = s_user[e] + s_part[e] + acc;
    }
}

extern "C" void kernel_launch(void* const* d_in, const int* in_sizes, int n_in,
                              void* d_out, int out_size, void* d_ws, size_t ws_size,
                              hipStream_t stream) {
    const int*   user_ids = (const int*)  d_in[0];
    const int*   item_ids = (const int*)  d_in[1];
    const float* features = (const float*)d_in[2];
    const float* user_emb = (const float*)d_in[3];
    const float* item_emb = (const float*)d_in[4];
    const float* feat_w1  = (const float*)d_in[5];
    const float* feat_b1  = (const float*)d_in[6];
    const float* feat_w2  = (const float*)d_in[7];
    const float* feat_b2  = (const float*)d_in[8];
    const float* w1       = (const float*)d_in[9];
    const float* b1       = (const float*)d_in[10];
    const float* w2       = (const float*)d_in[11];
    const float* b2       = (const float*)d_in[12];
    float* out = (float*)d_out;

    usernet_fused<<<BB, 256, 0, stream>>>(user_ids, item_ids, features,
                                          user_emb, item_emb,
                                          feat_w1, feat_b1, feat_w2, feat_b2,
                                          w1, b1, w2, b2, out);
}

// Round 2
// 927.547 us; speedup vs baseline: 2.5293x; 2.5293x over previous
//
#include <hip/hip_runtime.h>
#include <math.h>

#define BB 4096
#define LL 200
#define EE 128
#define FF 64

// LDS row pitches (bf16 elems). Chosen so pitch_bytes = 16*odd -> A-operand
// ds_read_b128 addresses hit all 8 16B-columns uniformly (conflict-free).
#define PITCH_F  72     // features K=64  (+8 pad), 144 B = 16*9
#define PITCH_FX 136    // fx       K=128 (+8 pad), 272 B = 16*17
#define PITCH_X3 264    // items|comp K=256 (+8 pad), 528 B = 16*33

typedef __attribute__((ext_vector_type(4))) float  floatx4;
typedef __attribute__((ext_vector_type(8))) short  shortx8;

#define MFMA16(a, b, c) __builtin_amdgcn_mfma_f32_16x16x32_bf16((a), (b), (c), 0, 0, 0)

__device__ __forceinline__ unsigned short f2bf(float f) {
    union { float f; unsigned u; } c; c.f = f;
    return (unsigned short)((c.u + 0x7fffu + ((c.u >> 16) & 1u)) >> 16);
}

// load 8 consecutive fp32, round to bf16, return MFMA B-fragment
__device__ __forceinline__ shortx8 load_bfrag(const float* p) {
    float4 v0 = ((const float4*)p)[0];
    float4 v1 = ((const float4*)p)[1];
    shortx8 r;
    r[0] = (short)f2bf(v0.x); r[1] = (short)f2bf(v0.y);
    r[2] = (short)f2bf(v0.z); r[3] = (short)f2bf(v0.w);
    r[4] = (short)f2bf(v1.x); r[5] = (short)f2bf(v1.y);
    r[6] = (short)f2bf(v1.z); r[7] = (short)f2bf(v1.w);
    return r;
}

__device__ __forceinline__ float waveMax(float v) {
    #pragma unroll
    for (int off = 32; off > 0; off >>= 1)
        v = fmaxf(v, __shfl_xor(v, off, 64));
    return v;
}
__device__ __forceinline__ float waveSum(float v) {
    #pragma unroll
    for (int off = 32; off > 0; off >>= 1)
        v += __shfl_xor(v, off, 64);
    return v;
}

__global__ __launch_bounds__(256, 2)
void usernet_mfma(const int* __restrict__ user_ids,
                  const int* __restrict__ item_ids,
                  const float* __restrict__ features,
                  const float* __restrict__ user_emb,
                  const float* __restrict__ item_emb,
                  const float* __restrict__ feat_w1,
                  const float* __restrict__ feat_b1,
                  const float* __restrict__ feat_w2,
                  const float* __restrict__ feat_b2,
                  const float* __restrict__ w1,
                  const float* __restrict__ b1,
                  const float* __restrict__ w2,
                  const float* __restrict__ b2,
                  float* __restrict__ out)
{
    __shared__ __align__(16) unsigned short s_feat[64 * PITCH_F];   //  9216 B
    __shared__ __align__(16) unsigned short s_fx  [64 * PITCH_FX];  // 17408 B
    __shared__ __align__(16) unsigned short s_x3  [64 * PITCH_X3];  // 33792 B
    __shared__ float s_user[EE];
    __shared__ float s_bias1[EE];   // u1 + feat_b1
    __shared__ float s_bias2[EE];   // feat_b2
    __shared__ float s_bias3[EE];   // u3 + b1
    __shared__ float s_w2[EE];
    __shared__ float s_lp[4][208];  // per-wave logit partials
    __shared__ float s_attn[208];
    __shared__ float s_red[8];
    __shared__ float s_part[EE];

    const int b    = blockIdx.x;
    const int tid  = threadIdx.x;
    const int lane = tid & 63;
    const int wv   = tid >> 6;         // wave id: owns output cols [32*wv, 32*wv+32)
    const int m    = lane & 15;
    const int q    = lane >> 4;
    const int n0   = wv * 32 + m;      // first owned col for this lane
    const int n1   = n0 + 16;

    // ---- persistent B fragments: weights (user cols folded out) ----
    shortx8 B1[2][2];   // feat_w1 features part, K=64
    shortx8 B2[4][2];   // feat_w2, K=128
    shortx8 B3[8][2];   // w1 item|comp part, K=256
    #pragma unroll
    for (int nt = 0; nt < 2; ++nt) {
        const int n = wv * 32 + nt * 16 + m;
        #pragma unroll
        for (int ks = 0; ks < 2; ++ks)
            B1[ks][nt] = load_bfrag(feat_w1 + (size_t)n * (EE + FF) + EE + ks * 32 + q * 8);
        #pragma unroll
        for (int ks = 0; ks < 4; ++ks)
            B2[ks][nt] = load_bfrag(feat_w2 + (size_t)n * EE + ks * 32 + q * 8);
        #pragma unroll
        for (int ks = 0; ks < 8; ++ks)
            B3[ks][nt] = load_bfrag(w1 + (size_t)n * (3 * EE) + EE + ks * 32 + q * 8);
    }

    // ---- user row + small biases ----
    if (tid < 32) {
        const int uid = user_ids[b];
        ((float4*)s_user)[tid] = ((const float4*)(user_emb + (size_t)uid * EE))[tid];
    }
    if (tid < EE) {
        s_bias2[tid] = feat_b2[tid];
        s_w2[tid]    = w2[tid];
    }
    __syncthreads();

    // ---- fp32 user folds: bias1 = W1a@user + feat_b1 ; bias3 = W3a@user + b1 ----
    {
        const int e    = tid & (EE - 1);
        const int half = tid >> 7;
        const float* wrow = half ? (w1 + (size_t)e * (3 * EE))
                                 : (feat_w1 + (size_t)e * (EE + FF));
        float acc = 0.f;
        #pragma unroll 8
        for (int k = 0; k < EE; ++k) acc += wrow[k] * s_user[k];
        if (half == 0) s_bias1[e] = acc + feat_b1[e];
        else           s_bias3[e] = acc + b1[e];
    }
    __syncthreads();

    const float bias1_0 = s_bias1[n0], bias1_1 = s_bias1[n1];
    const float bias2_0 = s_bias2[n0], bias2_1 = s_bias2[n1];
    const float bias3_0 = s_bias3[n0], bias3_1 = s_bias3[n1];
    const float w2_0    = s_w2[n0],    w2_1    = s_w2[n1];

    // ---- chunk loop: 13 M-tiles of 16 rows, in chunks of (4,4,4,1) tiles ----
    for (int ch = 0; ch < 4; ++ch) {
        const int row0 = ch * 64;
        const int ntl  = (ch < 3) ? 4 : 1;
        const int rows = ntl * 16;

        // stage features -> bf16 LDS [row][k] (pad rows = 0)
        for (int idx = tid; idx < rows * 16; idx += 256) {
            const int r = idx >> 4, c4 = idx & 15;
            const int l = row0 + r;
            float4 v = make_float4(0.f, 0.f, 0.f, 0.f);
            if (l < LL) v = ((const float4*)features)[((size_t)b * LL + l) * 16 + c4];
            ushort4 o; o.x = f2bf(v.x); o.y = f2bf(v.y); o.z = f2bf(v.z); o.w = f2bf(v.w);
            *(ushort4*)&s_feat[r * PITCH_F + c4 * 4] = o;
        }
        // stage gathered item rows -> bf16 LDS x3[row][0..127]
        for (int idx = tid; idx < rows * 32; idx += 256) {
            const int r = idx >> 5, c4 = idx & 31;
            const int l = row0 + r;
            float4 v = make_float4(0.f, 0.f, 0.f, 0.f);
            if (l < LL) {
                const int id = item_ids[(size_t)b * LL + l];
                v = ((const float4*)item_emb)[(size_t)id * 32 + c4];
            }
            ushort4 o; o.x = f2bf(v.x); o.y = f2bf(v.y); o.z = f2bf(v.z); o.w = f2bf(v.w);
            *(ushort4*)&s_x3[r * PITCH_X3 + c4 * 4] = o;
        }
        __syncthreads();

        // layer 1: fx = relu(feat @ W1f^T + bias1)
        for (int mt = 0; mt < ntl; ++mt) {
            floatx4 a0 = {0.f, 0.f, 0.f, 0.f}, a1 = {0.f, 0.f, 0.f, 0.f};
            const unsigned short* ap = s_feat + (mt * 16 + m) * PITCH_F + q * 8;
            #pragma unroll
            for (int ks = 0; ks < 2; ++ks) {
                shortx8 af = *(const shortx8*)(ap + ks * 32);
                a0 = MFMA16(af, B1[ks][0], a0);
                a1 = MFMA16(af, B1[ks][1], a1);
            }
            #pragma unroll
            for (int r = 0; r < 4; ++r) {
                const int row = mt * 16 + q * 4 + r;
                float v0 = a0[r] + bias1_0; v0 = v0 > 0.f ? v0 : 0.f;
                float v1 = a1[r] + bias1_1; v1 = v1 > 0.f ? v1 : 0.f;
                s_fx[row * PITCH_FX + n0] = f2bf(v0);
                s_fx[row * PITCH_FX + n1] = f2bf(v1);
            }
        }
        __syncthreads();

        // layer 2: comp = relu(fx @ W2^T + bias2) -> x3 cols 128..255
        for (int mt = 0; mt < ntl; ++mt) {
            floatx4 a0 = {0.f, 0.f, 0.f, 0.f}, a1 = {0.f, 0.f, 0.f, 0.f};
            const unsigned short* ap = s_fx + (mt * 16 + m) * PITCH_FX + q * 8;
            #pragma unroll
            for (int ks = 0; ks < 4; ++ks) {
                shortx8 af = *(const shortx8*)(ap + ks * 32);
                a0 = MFMA16(af, B2[ks][0], a0);
                a1 = MFMA16(af, B2[ks][1], a1);
            }
            #pragma unroll
            for (int r = 0; r < 4; ++r) {
                const int row = mt * 16 + q * 4 + r;
                float v0 = a0[r] + bias2_0; v0 = v0 > 0.f ? v0 : 0.f;
                float v1 = a1[r] + bias2_1; v1 = v1 > 0.f ? v1 : 0.f;
                s_x3[row * PITCH_X3 + EE + n0] = f2bf(v0);
                s_x3[row * PITCH_X3 + EE + n1] = f2bf(v1);
            }
        }
        __syncthreads();

        // layer 3: h = relu([items|comp] @ W3'^T + bias3); logit partial = sum_n w2[n]*h
        for (int mt = 0; mt < ntl; ++mt) {
            floatx4 a0 = {0.f, 0.f, 0.f, 0.f}, a1 = {0.f, 0.f, 0.f, 0.f};
            const unsigned short* ap = s_x3 + (mt * 16 + m) * PITCH_X3 + q * 8;
            #pragma unroll
            for (int ks = 0; ks < 8; ++ks) {
                shortx8 af = *(const shortx8*)(ap + ks * 32);
                a0 = MFMA16(af, B3[ks][0], a0);
                a1 = MFMA16(af, B3[ks][1], a1);
            }
            #pragma unroll
            for (int r = 0; r < 4; ++r) {
                float v0 = a0[r] + bias3_0; v0 = v0 > 0.f ? v0 : 0.f;
                float v1 = a1[r] + bias3_1; v1 = v1 > 0.f ? v1 : 0.f;
                float p = v0 * w2_0 + v1 * w2_1;
                p += __shfl_xor(p, 1, 64);   // reduce over the 16-lane m dim
                p += __shfl_xor(p, 2, 64);
                p += __shfl_xor(p, 4, 64);
                p += __shfl_xor(p, 8, 64);
                if (m == 0) s_lp[wv][row0 + mt * 16 + q * 4 + r] = p;
            }
        }
        __syncthreads();
    }

    // ---- softmax over L=200 ----
    const int wid = tid >> 6;
    float lv = -INFINITY;
    if (tid < LL)
        lv = b2[0] + s_lp[0][tid] + s_lp[1][tid] + s_lp[2][tid] + s_lp[3][tid];
    {
        float mx = waveMax(lv);
        if ((tid & 63) == 0) s_red[wid] = mx;
        __syncthreads();
        if (tid == 0)
            s_red[4] = fmaxf(fmaxf(s_red[0], s_red[1]), fmaxf(s_red[2], s_red[3]));
        __syncthreads();
    }
    const float gmax = s_red[4];
    __syncthreads();
    float ex = (tid < LL) ? __expf(lv - gmax) : 0.f;
    {
        float s = waveSum(ex);
        if ((tid & 63) == 0) s_red[wid] = s;
        __syncthreads();
        if (tid == 0) s_red[4] = s_red[0] + s_red[1] + s_red[2] + s_red[3];
        __syncthreads();
    }
    const float inv = 1.f / s_red[4];
    if (tid < LL) s_attn[tid] = ex * inv;
    __syncthreads();

    // ---- out[b] = user + sum_l attn[l] * item_emb[item_ids[b,l]]  (fp32) ----
    {
        const int e    = tid & (EE - 1);
        const int half = tid >> 7;
        float acc = 0.f;
        const int lstart = half * (LL / 2);
        for (int l = lstart; l < lstart + LL / 2; ++l) {
            const float a  = s_attn[l];
            const int  id  = item_ids[(size_t)b * LL + l];
            acc += a * item_emb[(size_t)id * EE + e];
        }
        if (half == 0) s_part[e] = acc;
        __syncthreads();
        if (half == 1)
            out[(size_t)b * EE + e] = s_user[e] + s_part[e] + acc;
    }
}

extern "C" void kernel_launch(void* const* d_in, const int* in_sizes, int n_in,
                              void* d_out, int out_size, void* d_ws, size_t ws_size,
                              hipStream_t stream) {
    const int*   user_ids = (const int*)  d_in[0];
    const int*   item_ids = (const int*)  d_in[1];
    const float* features = (const float*)d_in[2];
    const float* user_emb = (const float*)d_in[3];
    const float* item_emb = (const float*)d_in[4];
    const float* feat_w1  = (const float*)d_in[5];
    const float* feat_b1  = (const float*)d_in[6];
    const float* feat_w2  = (const float*)d_in[7];
    const float* feat_b2  = (const float*)d_in[8];
    const float* w1       = (const float*)d_in[9];
    const float* b1       = (const float*)d_in[10];
    const float* w2       = (const float*)d_in[11];
    const float* b2       = (const float*)d_in[12];
    float* out = (float*)d_out;

    usernet_mfma<<<BB, 256, 0, stream>>>(user_ids, item_ids, features,
                                         user_emb, item_emb,
                                         feat_w1, feat_b1, feat_w2, feat_b2,
                                         w1, b1, w2, b2, out);
}

// Round 3
// 767.491 us; speedup vs baseline: 3.0568x; 1.2085x over previous
//
#include <hip/hip_runtime.h>
#include <math.h>

#define BB 4096
#define LL 200
#define EE 128
#define FF 64
#define NTHREADS 512   // 8 waves; each wave owns 16 output columns (one N-tile)

// LDS row pitches (bf16 elems). pitch_bytes = 16*odd -> A-operand ds_read_b128
// 16B-column index = (9m+q) mod 8, uniform -> conflict-free.
#define PITCH_F  72     // features K=64  (+8 pad), 144 B = 16*9
#define PITCH_FX 136    // fx       K=128 (+8 pad), 272 B = 16*17
#define PITCH_X3 264    // items|comp K=256 (+8 pad), 528 B = 16*33

typedef __attribute__((ext_vector_type(4))) float  floatx4;
typedef __attribute__((ext_vector_type(8))) short  shortx8;

#define MFMA16(a, b, c) __builtin_amdgcn_mfma_f32_16x16x32_bf16((a), (b), (c), 0, 0, 0)

__device__ __forceinline__ unsigned short f2bf(float f) {
    union { float f; unsigned u; } c; c.f = f;
    return (unsigned short)((c.u + 0x7fffu + ((c.u >> 16) & 1u)) >> 16);
}

// load 8 consecutive fp32, round to bf16, return MFMA B-fragment
__device__ __forceinline__ shortx8 load_bfrag(const float* p) {
    float4 v0 = ((const float4*)p)[0];
    float4 v1 = ((const float4*)p)[1];
    shortx8 r;
    r[0] = (short)f2bf(v0.x); r[1] = (short)f2bf(v0.y);
    r[2] = (short)f2bf(v0.z); r[3] = (short)f2bf(v0.w);
    r[4] = (short)f2bf(v1.x); r[5] = (short)f2bf(v1.y);
    r[6] = (short)f2bf(v1.z); r[7] = (short)f2bf(v1.w);
    return r;
}

__device__ __forceinline__ float waveMax(float v) {
    #pragma unroll
    for (int off = 32; off > 0; off >>= 1)
        v = fmaxf(v, __shfl_xor(v, off, 64));
    return v;
}
__device__ __forceinline__ float waveSum(float v) {
    #pragma unroll
    for (int off = 32; off > 0; off >>= 1)
        v += __shfl_xor(v, off, 64);
    return v;
}

__global__ __launch_bounds__(NTHREADS, 4)
void usernet_mfma(const int* __restrict__ user_ids,
                  const int* __restrict__ item_ids,
                  const float* __restrict__ features,
                  const float* __restrict__ user_emb,
                  const float* __restrict__ item_emb,
                  const float* __restrict__ feat_w1,
                  const float* __restrict__ feat_b1,
                  const float* __restrict__ feat_w2,
                  const float* __restrict__ feat_b2,
                  const float* __restrict__ w1,
                  const float* __restrict__ b1,
                  const float* __restrict__ w2,
                  const float* __restrict__ b2,
                  float* __restrict__ out)
{
    __shared__ __align__(16) unsigned short s_feat[64 * PITCH_F];   //  9216 B
    __shared__ __align__(16) unsigned short s_fx  [64 * PITCH_FX];  // 17408 B
    __shared__ __align__(16) unsigned short s_x3  [64 * PITCH_X3];  // 33792 B
    __shared__ float s_user[EE];
    __shared__ float s_bias1[EE];   // u1 + feat_b1
    __shared__ float s_bias2[EE];   // feat_b2
    __shared__ float s_bias3[EE];   // u3 + b1
    __shared__ float s_w2[EE];
    __shared__ float s_lp[8][208];  // per-wave logit partials (6656 B)
    __shared__ float s_attn[208];
    __shared__ float s_red[12];
    __shared__ float s_part[4][EE];

    const int b    = blockIdx.x;
    const int tid  = threadIdx.x;
    const int lane = tid & 63;
    const int wv   = tid >> 6;         // wave id 0..7: owns output cols [16*wv, 16*wv+16)
    const int m    = lane & 15;
    const int q    = lane >> 4;
    const int n0   = wv * 16 + m;      // owned output col for this lane

    // ---- persistent B fragments (56 VGPRs/wave; user cols folded out) ----
    shortx8 B1[2];   // feat_w1 features part, K=64
    shortx8 B2[4];   // feat_w2, K=128
    shortx8 B3[8];   // w1 item|comp part, K=256
    #pragma unroll
    for (int ks = 0; ks < 2; ++ks)
        B1[ks] = load_bfrag(feat_w1 + (size_t)n0 * (EE + FF) + EE + ks * 32 + q * 8);
    #pragma unroll
    for (int ks = 0; ks < 4; ++ks)
        B2[ks] = load_bfrag(feat_w2 + (size_t)n0 * EE + ks * 32 + q * 8);
    #pragma unroll
    for (int ks = 0; ks < 8; ++ks)
        B3[ks] = load_bfrag(w1 + (size_t)n0 * (3 * EE) + EE + ks * 32 + q * 8);

    // ---- user row + small vectors ----
    if (tid < 32) {
        const int uid = user_ids[b];
        ((float4*)s_user)[tid] = ((const float4*)(user_emb + (size_t)uid * EE))[tid];
    }
    if (tid >= 64 && tid < 64 + EE) {
        s_bias2[tid - 64] = feat_b2[tid - 64];
        s_w2[tid - 64]    = w2[tid - 64];
    }
    __syncthreads();

    // ---- fp32 user folds: bias1 = W1a@user + feat_b1 ; bias3 = W3a@user + b1 ----
    if (tid < 256) {
        const int e    = tid & (EE - 1);
        const int half = tid >> 7;
        const float* wrow = half ? (w1 + (size_t)e * (3 * EE))
                                 : (feat_w1 + (size_t)e * (EE + FF));
        float acc = 0.f;
        #pragma unroll 8
        for (int k = 0; k < EE; ++k) acc += wrow[k] * s_user[k];
        if (half == 0) s_bias1[e] = acc + feat_b1[e];
        else           s_bias3[e] = acc + b1[e];
    }
    __syncthreads();

    const float bias1_0 = s_bias1[n0];
    const float bias2_0 = s_bias2[n0];
    const float bias3_0 = s_bias3[n0];
    const float w2_0    = s_w2[n0];

    // ---- chunk loop: 13 M-tiles of 16 rows, in chunks of (4,4,4,1) tiles ----
    for (int ch = 0; ch < 4; ++ch) {
        const int row0 = ch * 64;
        const int ntl  = (ch < 3) ? 4 : 1;
        const int rows = ntl * 16;

        // stage features -> bf16 LDS [row][k] (pad rows = 0)
        for (int idx = tid; idx < rows * 16; idx += NTHREADS) {
            const int r = idx >> 4, c4 = idx & 15;
            const int l = row0 + r;
            float4 v = make_float4(0.f, 0.f, 0.f, 0.f);
            if (l < LL) v = ((const float4*)features)[((size_t)b * LL + l) * 16 + c4];
            ushort4 o; o.x = f2bf(v.x); o.y = f2bf(v.y); o.z = f2bf(v.z); o.w = f2bf(v.w);
            *(ushort4*)&s_feat[r * PITCH_F + c4 * 4] = o;
        }
        // stage gathered item rows -> bf16 LDS x3[row][0..127]
        for (int idx = tid; idx < rows * 32; idx += NTHREADS) {
            const int r = idx >> 5, c4 = idx & 31;
            const int l = row0 + r;
            float4 v = make_float4(0.f, 0.f, 0.f, 0.f);
            if (l < LL) {
                const int id = item_ids[(size_t)b * LL + l];
                v = ((const float4*)item_emb)[(size_t)id * 32 + c4];
            }
            ushort4 o; o.x = f2bf(v.x); o.y = f2bf(v.y); o.z = f2bf(v.z); o.w = f2bf(v.w);
            *(ushort4*)&s_x3[r * PITCH_X3 + c4 * 4] = o;
        }
        __syncthreads();

        // layer 1: fx = relu(feat @ W1f^T + bias1)
        for (int mt = 0; mt < ntl; ++mt) {
            floatx4 a0 = {0.f, 0.f, 0.f, 0.f};
            const unsigned short* ap = s_feat + (mt * 16 + m) * PITCH_F + q * 8;
            #pragma unroll
            for (int ks = 0; ks < 2; ++ks) {
                shortx8 af = *(const shortx8*)(ap + ks * 32);
                a0 = MFMA16(af, B1[ks], a0);
            }
            #pragma unroll
            for (int r = 0; r < 4; ++r) {
                const int row = mt * 16 + q * 4 + r;
                float v0 = a0[r] + bias1_0; v0 = v0 > 0.f ? v0 : 0.f;
                s_fx[row * PITCH_FX + n0] = f2bf(v0);
            }
        }
        __syncthreads();

        // layer 2: comp = relu(fx @ W2^T + bias2) -> x3 cols 128..255
        for (int mt = 0; mt < ntl; ++mt) {
            floatx4 a0 = {0.f, 0.f, 0.f, 0.f};
            const unsigned short* ap = s_fx + (mt * 16 + m) * PITCH_FX + q * 8;
            #pragma unroll
            for (int ks = 0; ks < 4; ++ks) {
                shortx8 af = *(const shortx8*)(ap + ks * 32);
                a0 = MFMA16(af, B2[ks], a0);
            }
            #pragma unroll
            for (int r = 0; r < 4; ++r) {
                const int row = mt * 16 + q * 4 + r;
                float v0 = a0[r] + bias2_0; v0 = v0 > 0.f ? v0 : 0.f;
                s_x3[row * PITCH_X3 + EE + n0] = f2bf(v0);
            }
        }
        __syncthreads();

        // layer 3: h = relu([items|comp] @ W3'^T + bias3); logit partial = w2[n]*h
        for (int mt = 0; mt < ntl; ++mt) {
            floatx4 a0 = {0.f, 0.f, 0.f, 0.f};
            const unsigned short* ap = s_x3 + (mt * 16 + m) * PITCH_X3 + q * 8;
            #pragma unroll
            for (int ks = 0; ks < 8; ++ks) {
                shortx8 af = *(const shortx8*)(ap + ks * 32);
                a0 = MFMA16(af, B3[ks], a0);
            }
            #pragma unroll
            for (int r = 0; r < 4; ++r) {
                float v0 = a0[r] + bias3_0; v0 = v0 > 0.f ? v0 : 0.f;
                float p = v0 * w2_0;
                p += __shfl_xor(p, 1, 64);   // reduce over the 16-lane n dim
                p += __shfl_xor(p, 2, 64);
                p += __shfl_xor(p, 4, 64);
                p += __shfl_xor(p, 8, 64);
                if (m == 0) s_lp[wv][row0 + mt * 16 + q * 4 + r] = p;
            }
        }
        __syncthreads();
    }

    // ---- softmax over L=200 ----
    const int wid = tid >> 6;
    float lv = -INFINITY;
    if (tid < LL) {
        lv = b2[0];
        #pragma unroll
        for (int w = 0; w < 8; ++w) lv += s_lp[w][tid];
    }
    {
        float mx = waveMax(lv);
        if ((tid & 63) == 0) s_red[wid] = mx;
        __syncthreads();
        if (tid == 0) {
            float g = s_red[0];
            #pragma unroll
            for (int w = 1; w < 8; ++w) g = fmaxf(g, s_red[w]);
            s_red[8] = g;
        }
        __syncthreads();
    }
    const float gmax = s_red[8];
    __syncthreads();
    float ex = (tid < LL) ? __expf(lv - gmax) : 0.f;
    {
        float s = waveSum(ex);
        if ((tid & 63) == 0) s_red[wid] = s;
        __syncthreads();
        if (tid == 0) {
            float g = 0.f;
            #pragma unroll
            for (int w = 0; w < 8; ++w) g += s_red[w];
            s_red[8] = g;
        }
        __syncthreads();
    }
    const float inv = 1.f / s_red[8];
    if (tid < LL) s_attn[tid] = ex * inv;
    __syncthreads();

    // ---- out[b] = user + sum_l attn[l] * item_emb[item_ids[b,l]]  (fp32) ----
    {
        const int e = tid & (EE - 1);
        const int g = tid >> 7;            // 0..3, each covers 50 l's
        float acc = 0.f;
        const int lstart = g * (LL / 4);
        for (int l = lstart; l < lstart + LL / 4; ++l) {
            const float a  = s_attn[l];
            const int  id  = item_ids[(size_t)b * LL + l];
            acc += a * item_emb[(size_t)id * EE + e];
        }
        s_part[g][e] = acc;
        __syncthreads();
        if (tid < EE)
            out[(size_t)b * EE + tid] = s_user[tid] + s_part[0][tid] + s_part[1][tid]
                                      + s_part[2][tid] + s_part[3][tid];
    }
}

extern "C" void kernel_launch(void* const* d_in, const int* in_sizes, int n_in,
                              void* d_out, int out_size, void* d_ws, size_t ws_size,
                              hipStream_t stream) {
    const int*   user_ids = (const int*)  d_in[0];
    const int*   item_ids = (const int*)  d_in[1];
    const float* features = (const float*)d_in[2];
    const float* user_emb = (const float*)d_in[3];
    const float* item_emb = (const float*)d_in[4];
    const float* feat_w1  = (const float*)d_in[5];
    const float* feat_b1  = (const float*)d_in[6];
    const float* feat_w2  = (const float*)d_in[7];
    const float* feat_b2  = (const float*)d_in[8];
    const float* w1       = (const float*)d_in[9];
    const float* b1       = (const float*)d_in[10];
    const float* w2       = (const float*)d_in[11];
    const float* b2       = (const float*)d_in[12];
    float* out = (float*)d_out;

    usernet_mfma<<<BB, NTHREADS, 0, stream>>>(user_ids, item_ids, features,
                                              user_emb, item_emb,
                                              feat_w1, feat_b1, feat_w2, feat_b2,
                                              w1, b1, w2, b2, out);
}